// Round 3
// baseline (388.914 us; speedup 1.0000x reference)
//
#include <hip/hip_runtime.h>
#include <math.h>

#define Bn 2048
#define Sn 277
#define Rn 80
#define Ln 12
#define Zn 56
#define NROWS (Bn * Sn)                   // 567296
#define NBLK_BCE 2216                     // 256 rows per block (64 rows/iter x 4 iters)
#define ITERS 4
#define NMOM 32                           // moment blocks
#define MROWS (Bn / NMOM)                 // 64 mu-rows per moment block
#define NBLK_TOT (NBLK_BCE + NMOM)
#define NWAVE_BCE (NBLK_BCE * 4)          // 8864 per-wave partials

// ws layout (bytes):
//   [0,     1280)   u32  cmask_sw[80][4]  per-(rule,lane) 20-bit mask (setup)
//   [1280, 36736)   float bce_partial[8864]  one float PER WAVE (no zeroing)
//   [36736, 49280)  float var_g[3136]     (atomicAdd -> memset 0)
//   [49280, 49504)  float avg_g[56]       (atomicAdd -> memset 0)
#define WS_CM  0
#define WS_BCE 1280
#define WS_VAR 36736
#define WS_AVG 49280

__device__ __forceinline__ float qsum4(float v) {
    // butterfly sum within each 4-lane quad via DPP quad_perm (no DS ops)
    int t = __builtin_amdgcn_update_dpp(0, __float_as_int(v), 0xB1, 0xF, 0xF, true); // [1,0,3,2]
    v += __int_as_float(t);
    t = __builtin_amdgcn_update_dpp(0, __float_as_int(v), 0x4E, 0xF, 0xF, true);     // [2,3,0,1]
    v += __int_as_float(t);
    return v;
}

__global__ __launch_bounds__(256) void setup_kernel(
    const float* __restrict__ masks, const int* __restrict__ lhs, char* __restrict__ ws)
{
    unsigned* cmask_sw = (unsigned*)(ws + WS_CM);
    for (int idx = threadIdx.x; idx < Rn * 4; idx += 256) {
        const int r = idx >> 2, c = idx & 3;
        const int l = lhs[r];
        unsigned bits = 0u;
        for (int k = 0; k < 5; ++k)
            for (int comp = 0; comp < 4; ++comp) {
                const int j = 16 * k + 4 * c + comp;
                if (masks[l * Rn + j] > 0.5f) bits |= (1u << (4 * k + comp));
            }
        cmask_sw[idx] = bits;
    }
}

// Concurrency fix (request-granularity theory falsified in R2: coalesced-LDS
// and quad-direct both hit 3.0 TB/s at 23-28% occupancy). This version removes
// ALL barriers/LDS from the BCE path and forces the 64-VGPR occupancy tier
// (waves/EU halves at vgpr=64/128): 8 blocks/CU, 32 waves/CU, each wave
// independently looping {10-load burst -> compute} with no convoy sync, so
// loads stay continuously outstanding device-wide.
__global__ __launch_bounds__(256, 8) void main_kernel(
    const float* __restrict__ x, const float* __restrict__ recon,
    const float* __restrict__ mu, char* __restrict__ ws)
{
    const int tid = threadIdx.x;

    if (blockIdx.x < NMOM) {
        // ---------------- moments: 32 blocks x 64 mu-rows ----------------
        __shared__ float sm[MROWS * Zn];              // 14336 B
        float* var_g = (float*)(ws + WS_VAR);
        float* avg_g = (float*)(ws + WS_AVG);
        const int m = blockIdx.x;
        const float* src = mu + (size_t)m * MROWS * Zn;
        for (int i = tid; i < MROWS * Zn; i += 256) sm[i] = src[i];
        __syncthreads();

        #pragma unroll 1
        for (int k = 0; k < 13; ++k) {
            const int p = tid + 256 * k;
            if (p < Zn * Zn) {
                const int i = p / Zn, j = p - i * Zn;
                float a = 0.0f;
                #pragma unroll 8
                for (int r = 0; r < MROWS; ++r) a = fmaf(sm[r * Zn + i], sm[r * Zn + j], a);
                atomicAdd(&var_g[p], a);
            }
        }
        if (tid < Zn) {
            float s = 0.0f;
            #pragma unroll 8
            for (int r = 0; r < MROWS; ++r) s += sm[r * Zn + tid];
            atomicAdd(&avg_g[tid], s);
        }
        return;
    }

    // ---------------- BCE: 1 row/quad, 4 iters, no LDS, no barriers ----------------
    const int bid = blockIdx.x - NMOM;
    const unsigned* cmask_sw = (const unsigned*)(ws + WS_CM);
    float* bce_partial = (float*)(ws + WS_BCE);

    const int q = tid >> 2;              // quad 0..63 = row within 64-row chunk
    const int c = tid & 3;               // lane within quad
    const float4* xp = (const float4*)x;
    const float4* rp = (const float4*)recon;
    // float4 index of this thread's first element; block covers 256 contiguous rows
    int off = (bid * 256 + q) * 20 + c;  // max ~11.3M < 2^31

    auto dotc = [](const float4 v, float base_) {
        return fmaf(v.x, base_, fmaf(v.y, base_ + 1.f, fmaf(v.z, base_ + 2.f, v.w * (base_ + 3.f))));
    };

    float ss = 0.0f;
    #pragma unroll 1
    for (int it = 0; it < ITERS; ++it, off += 64 * 20) {
        float4 X[5], Rv[5];
        #pragma unroll
        for (int k = 0; k < 5; ++k) X[k]  = xp[off + 4 * k];
        #pragma unroll
        for (int k = 0; k < 5; ++k) Rv[k] = rp[off + 4 * k];
        __builtin_amdgcn_sched_barrier(0);   // keep the 10-load burst above compute

        // argmax via dot with index weights (x is exactly one-hot)
        float dl = dotc(X[0], 0.f) + dotc(X[1], 16.f) + dotc(X[2], 32.f)
                 + dotc(X[3], 48.f) + dotc(X[4], 64.f);
        float xs = 0.f;
        #pragma unroll
        for (int k = 0; k < 5; ++k)
            xs += ((X[k].x + X[k].y) + (X[k].z + X[k].w));
        dl = fmaf((float)(4 * c), xs, dl);
        const int amax = (int)(qsum4(dl) + 0.5f);

        const unsigned bits = cmask_sw[(amax << 2) | c];   // L1-hot dword

        // mask in place (reuse Rv registers: keeps body in the 64-VGPR tier)
        #pragma unroll
        for (int k = 0; k < 5; ++k) {
            Rv[k].x = ((bits >> (4 * k + 0)) & 1u) ? Rv[k].x : 0.f;
            Rv[k].y = ((bits >> (4 * k + 1)) & 1u) ? Rv[k].y : 0.f;
            Rv[k].z = ((bits >> (4 * k + 2)) & 1u) ? Rv[k].z : 0.f;
            Rv[k].w = ((bits >> (4 * k + 3)) & 1u) ? Rv[k].w : 0.f;
        }
        float dd = 0.f;
        #pragma unroll
        for (int k = 0; k < 5; ++k)
            dd += ((Rv[k].x + Rv[k].y) + (Rv[k].z + Rv[k].w));
        const float invd = __builtin_amdgcn_rcpf(qsum4(dd));

        const int ka = amax >> 4;
        const int ca = (amax >> 2) & 3;
        const int comp = amax & 3;
        const bool owner = (c == ca);

        // sum(log(1-t)) = log(prod(1-t)); product can only hit 0 if some t==1
        // exactly -> guarded per-element fallback (from regs) keeps clamp semantics.
        float p = 1.0f;
        float ta = 1.0f;
        #pragma unroll
        for (int k = 0; k < 5; ++k) {
            const float t0 = fminf(Rv[k].x * invd, 1.f);
            const float t1 = fminf(Rv[k].y * invd, 1.f);
            const float t2 = fminf(Rv[k].z * invd, 1.f);
            const float t3 = fminf(Rv[k].w * invd, 1.f);
            p *= ((1.f - t0) * (1.f - t1)) * ((1.f - t2) * (1.f - t3));
            if (owner && k == ka)
                ta = (comp == 0) ? t0 : (comp == 1) ? t1 : (comp == 2) ? t2 : t3;
        }
        if (p > 0.0f) {
            ss += __builtin_amdgcn_logf(p) * 0.69314718055994531f;   // log2 -> ln
        } else {
            // astronomically rare: per-element with clamps (data already in regs)
            #pragma unroll
            for (int k = 0; k < 5; ++k) {
                ss += fmaxf(__logf(1.f - fminf(Rv[k].x * invd, 1.f)), -100.f)
                    + fmaxf(__logf(1.f - fminf(Rv[k].y * invd, 1.f)), -100.f)
                    + fmaxf(__logf(1.f - fminf(Rv[k].z * invd, 1.f)), -100.f)
                    + fmaxf(__logf(1.f - fminf(Rv[k].w * invd, 1.f)), -100.f);
            }
        }
        if (owner)
            ss += fmaxf(__logf(ta), -100.f) - fmaxf(__logf(1.f - ta), -100.f);
    }

    // wave reduction: quad DPP + 4 shuffles, one float store per wave
    ss = qsum4(ss);
    ss += __shfl_xor(ss, 4);
    ss += __shfl_xor(ss, 8);
    ss += __shfl_xor(ss, 16);
    ss += __shfl_xor(ss, 32);
    if ((tid & 63) == 0)
        bce_partial[bid * 4 + (tid >> 6)] = ss;
}

__global__ __launch_bounds__(256) void finalize_kernel(
    const char* __restrict__ ws, float* __restrict__ out)
{
    const float* bce_partial = (const float*)(ws + WS_BCE);
    const float* var_g = (const float*)(ws + WS_VAR);
    const float* avg_g = (const float*)(ws + WS_AVG);
    __shared__ double sb[4];
    __shared__ float sv[4], sa[4];
    const int tid = threadIdx.x;

    double bsum = 0.0;
    for (int i = tid; i < NWAVE_BCE; i += 256) bsum += (double)bce_partial[i];

    float vsum = 0.0f;
    for (int p = tid; p < Zn * Zn; p += 256) {
        const int i = p / Zn, j = p - i * Zn;
        const float e = var_g[p] * (1.0f / (float)Bn) - ((i == j) ? 1.0f : 0.0f);
        vsum += fabsf(e);
    }
    float asum = 0.0f;
    for (int z = tid; z < Zn; z += 256) { const float a = avg_g[z]; asum += a * a; }

    #pragma unroll
    for (int o = 32; o; o >>= 1) {
        bsum += __shfl_xor(bsum, o);
        vsum += __shfl_xor(vsum, o);
        asum += __shfl_xor(asum, o);
    }
    if ((tid & 63) == 0) { const int w = tid >> 6; sb[w] = bsum; sv[w] = vsum; sa[w] = asum; }
    __syncthreads();
    if (tid == 0) {
        const double tb = (sb[0] + sb[1]) + (sb[2] + sb[3]);
        const double tv = (double)((sv[0] + sv[1]) + (sv[2] + sv[3]));
        const double ta = (double)((sa[0] + sa[1]) + (sa[2] + sa[3]));
        const double bce = -tb / ((double)Sn * (double)Bn);
        const double mom = ta / ((double)Bn * (double)Bn * (double)Zn)
                         + tv / ((double)Zn * (double)Zn);
        out[0] = (float)(bce + mom);
    }
}

extern "C" void kernel_launch(void* const* d_in, const int* in_sizes, int n_in,
                              void* d_out, int out_size, void* d_ws, size_t ws_size,
                              hipStream_t stream)
{
    const float* x     = (const float*)d_in[0];
    const float* recon = (const float*)d_in[1];
    const float* mu    = (const float*)d_in[2];
    // d_in[3] = log_var: unused by the reference
    const float* masks = (const float*)d_in[4];
    const int*   lhs   = (const int*)d_in[5];
    float* out = (float*)d_out;
    char* ws = (char*)d_ws;

    hipMemsetAsync(ws + WS_VAR, 0, 12544 + 224, stream);   // atomic accumulators only
    setup_kernel<<<1, 256, 0, stream>>>(masks, lhs, ws);
    main_kernel<<<NBLK_TOT, 256, 0, stream>>>(x, recon, mu, ws);
    finalize_kernel<<<1, 256, 0, stream>>>(ws, out);
}

// Round 4
// 361.948 us; speedup vs baseline: 1.0745x; 1.0745x over previous
//
#include <hip/hip_runtime.h>
#include <math.h>

#define Bn 2048
#define Sn 277
#define Rn 80
#define Ln 12
#define Zn 56
#define NROWS (Bn * Sn)                   // 567296
#define NBLK_BCE 2216                     // 256 rows per block (64 rows/iter x 4 iters)
#define ITERS 4
#define NMOM 32                           // moment blocks
#define MROWS (Bn / NMOM)                 // 64 mu-rows per moment block
#define NBLK_TOT (NBLK_BCE + NMOM)
#define NWAVE_BCE (NBLK_BCE * 4)          // 8864 per-wave partials

// ws layout (bytes):
//   [0,     1280)   u32  cmask_sw[80][4]  per-(rule,lane) 20-bit mask (setup)
//   [1280, 36736)   float bce_partial[8864]  one float PER WAVE (no zeroing)
//   [36736, 49280)  float var_g[3136]     (atomicAdd -> memset 0)
//   [49280, 49504)  float avg_g[56]       (atomicAdd -> memset 0)
#define WS_CM  0
#define WS_BCE 1280
#define WS_VAR 36736
#define WS_AVG 49280

typedef float f4 __attribute__((ext_vector_type(4)));

__device__ __forceinline__ float qsum4(float v) {
    // butterfly sum within each 4-lane quad via DPP quad_perm (no DS ops)
    int t = __builtin_amdgcn_update_dpp(0, __float_as_int(v), 0xB1, 0xF, 0xF, true); // [1,0,3,2]
    v += __int_as_float(t);
    t = __builtin_amdgcn_update_dpp(0, __float_as_int(v), 0x4E, 0xF, 0xF, true);     // [2,3,0,1]
    v += __int_as_float(t);
    return v;
}

__global__ __launch_bounds__(256) void setup_kernel(
    const float* __restrict__ masks, const int* __restrict__ lhs, char* __restrict__ ws)
{
    unsigned* cmask_sw = (unsigned*)(ws + WS_CM);
    for (int idx = threadIdx.x; idx < Rn * 4; idx += 256) {
        const int r = idx >> 2, c = idx & 3;
        const int l = lhs[r];
        unsigned bits = 0u;
        for (int k = 0; k < 5; ++k)
            for (int comp = 0; comp < 4; ++comp) {
                const int j = 16 * k + 4 * c + comp;
                if (masks[l * Rn + j] > 0.5f) bits |= (1u << (4 * k + comp));
            }
        cmask_sw[idx] = bits;
    }
}

// Cache-policy experiment. R0-R3 established: request granularity, occupancy
// (23->68%), MLP depth, and barriers are ALL flat at ~2.9-3.0 TB/s delivered
// (HBM only 1.45 TB/s = 18%; other half served by L3 hits, FETCH 183 of
// 363 MB). The untested lever is allocation policy: these are pure once-
// touched streams, so every request allocates L2/L3 lines for nothing.
// __builtin_nontemporal_load sets the nt bit (streaming / no-reuse).
// Discriminator: FETCH_SIZE -> ~360 MB means nt reached the L3; dur then
// tells us whether the ~3 TB/s wall was the allocate/hit path (drops) or a
// genuine read-path ceiling (flat -> roofline).
__global__ __launch_bounds__(256, 4) void main_kernel(
    const float* __restrict__ x, const float* __restrict__ recon,
    const float* __restrict__ mu, char* __restrict__ ws)
{
    const int tid = threadIdx.x;

    if (blockIdx.x < NMOM) {
        // ---------------- moments: 32 blocks x 64 mu-rows ----------------
        __shared__ float sm[MROWS * Zn];              // 14336 B
        float* var_g = (float*)(ws + WS_VAR);
        float* avg_g = (float*)(ws + WS_AVG);
        const int m = blockIdx.x;
        const float* src = mu + (size_t)m * MROWS * Zn;
        for (int i = tid; i < MROWS * Zn; i += 256) sm[i] = src[i];
        __syncthreads();

        #pragma unroll 1
        for (int k = 0; k < 13; ++k) {
            const int p = tid + 256 * k;
            if (p < Zn * Zn) {
                const int i = p / Zn, j = p - i * Zn;
                float a = 0.0f;
                #pragma unroll 8
                for (int r = 0; r < MROWS; ++r) a = fmaf(sm[r * Zn + i], sm[r * Zn + j], a);
                atomicAdd(&var_g[p], a);
            }
        }
        if (tid < Zn) {
            float s = 0.0f;
            #pragma unroll 8
            for (int r = 0; r < MROWS; ++r) s += sm[r * Zn + tid];
            atomicAdd(&avg_g[tid], s);
        }
        return;
    }

    // ---------------- BCE: 1 row/quad, 4 iters, no LDS, nt streaming loads ----------------
    const int bid = blockIdx.x - NMOM;
    const unsigned* cmask_sw = (const unsigned*)(ws + WS_CM);
    float* bce_partial = (float*)(ws + WS_BCE);

    const int q = tid >> 2;              // quad 0..63 = row within 64-row chunk
    const int c = tid & 3;               // lane within quad
    const f4* xp = (const f4*)x;
    const f4* rp = (const f4*)recon;
    // float4 index of this thread's first element; block covers 256 contiguous rows
    int off = (bid * 256 + q) * 20 + c;  // max ~11.3M < 2^31

    auto dotc = [](const f4 v, float base_) {
        return fmaf(v.x, base_, fmaf(v.y, base_ + 1.f, fmaf(v.z, base_ + 2.f, v.w * (base_ + 3.f))));
    };

    float ss = 0.0f;
    #pragma unroll 1
    for (int it = 0; it < ITERS; ++it, off += 64 * 20) {
        f4 X[5], Rv[5];
        #pragma unroll
        for (int k = 0; k < 5; ++k) X[k]  = __builtin_nontemporal_load(&xp[off + 4 * k]);
        #pragma unroll
        for (int k = 0; k < 5; ++k) Rv[k] = __builtin_nontemporal_load(&rp[off + 4 * k]);
        __builtin_amdgcn_sched_barrier(0);   // keep the 10-load burst above compute

        // argmax via dot with index weights (x is exactly one-hot)
        float dl = dotc(X[0], 0.f) + dotc(X[1], 16.f) + dotc(X[2], 32.f)
                 + dotc(X[3], 48.f) + dotc(X[4], 64.f);
        float xs = 0.f;
        #pragma unroll
        for (int k = 0; k < 5; ++k)
            xs += ((X[k].x + X[k].y) + (X[k].z + X[k].w));
        dl = fmaf((float)(4 * c), xs, dl);
        const int amax = (int)(qsum4(dl) + 0.5f);

        const unsigned bits = cmask_sw[(amax << 2) | c];   // L1-hot dword

        // mask in place (reuse Rv registers)
        #pragma unroll
        for (int k = 0; k < 5; ++k) {
            Rv[k].x = ((bits >> (4 * k + 0)) & 1u) ? Rv[k].x : 0.f;
            Rv[k].y = ((bits >> (4 * k + 1)) & 1u) ? Rv[k].y : 0.f;
            Rv[k].z = ((bits >> (4 * k + 2)) & 1u) ? Rv[k].z : 0.f;
            Rv[k].w = ((bits >> (4 * k + 3)) & 1u) ? Rv[k].w : 0.f;
        }
        float dd = 0.f;
        #pragma unroll
        for (int k = 0; k < 5; ++k)
            dd += ((Rv[k].x + Rv[k].y) + (Rv[k].z + Rv[k].w));
        const float invd = __builtin_amdgcn_rcpf(qsum4(dd));

        const int ka = amax >> 4;
        const int ca = (amax >> 2) & 3;
        const int comp = amax & 3;
        const bool owner = (c == ca);

        // sum(log(1-t)) = log(prod(1-t)); product can only hit 0 if some t==1
        // exactly -> guarded per-element fallback (from regs) keeps clamp semantics.
        float p = 1.0f;
        float ta = 1.0f;
        #pragma unroll
        for (int k = 0; k < 5; ++k) {
            const float t0 = fminf(Rv[k].x * invd, 1.f);
            const float t1 = fminf(Rv[k].y * invd, 1.f);
            const float t2 = fminf(Rv[k].z * invd, 1.f);
            const float t3 = fminf(Rv[k].w * invd, 1.f);
            p *= ((1.f - t0) * (1.f - t1)) * ((1.f - t2) * (1.f - t3));
            if (owner && k == ka)
                ta = (comp == 0) ? t0 : (comp == 1) ? t1 : (comp == 2) ? t2 : t3;
        }
        if (p > 0.0f) {
            ss += __builtin_amdgcn_logf(p) * 0.69314718055994531f;   // log2 -> ln
        } else {
            // astronomically rare: per-element with clamps (data already in regs)
            #pragma unroll
            for (int k = 0; k < 5; ++k) {
                ss += fmaxf(__logf(1.f - fminf(Rv[k].x * invd, 1.f)), -100.f)
                    + fmaxf(__logf(1.f - fminf(Rv[k].y * invd, 1.f)), -100.f)
                    + fmaxf(__logf(1.f - fminf(Rv[k].z * invd, 1.f)), -100.f)
                    + fmaxf(__logf(1.f - fminf(Rv[k].w * invd, 1.f)), -100.f);
            }
        }
        if (owner)
            ss += fmaxf(__logf(ta), -100.f) - fmaxf(__logf(1.f - ta), -100.f);
    }

    // wave reduction: quad DPP + 4 shuffles, one float store per wave
    ss = qsum4(ss);
    ss += __shfl_xor(ss, 4);
    ss += __shfl_xor(ss, 8);
    ss += __shfl_xor(ss, 16);
    ss += __shfl_xor(ss, 32);
    if ((tid & 63) == 0)
        bce_partial[bid * 4 + (tid >> 6)] = ss;
}

__global__ __launch_bounds__(256) void finalize_kernel(
    const char* __restrict__ ws, float* __restrict__ out)
{
    const float* bce_partial = (const float*)(ws + WS_BCE);
    const float* var_g = (const float*)(ws + WS_VAR);
    const float* avg_g = (const float*)(ws + WS_AVG);
    __shared__ double sb[4];
    __shared__ float sv[4], sa[4];
    const int tid = threadIdx.x;

    double bsum = 0.0;
    for (int i = tid; i < NWAVE_BCE; i += 256) bsum += (double)bce_partial[i];

    float vsum = 0.0f;
    for (int p = tid; p < Zn * Zn; p += 256) {
        const int i = p / Zn, j = p - i * Zn;
        const float e = var_g[p] * (1.0f / (float)Bn) - ((i == j) ? 1.0f : 0.0f);
        vsum += fabsf(e);
    }
    float asum = 0.0f;
    for (int z = tid; z < Zn; z += 256) { const float a = avg_g[z]; asum += a * a; }

    #pragma unroll
    for (int o = 32; o; o >>= 1) {
        bsum += __shfl_xor(bsum, o);
        vsum += __shfl_xor(vsum, o);
        asum += __shfl_xor(asum, o);
    }
    if ((tid & 63) == 0) { const int w = tid >> 6; sb[w] = bsum; sv[w] = vsum; sa[w] = asum; }
    __syncthreads();
    if (tid == 0) {
        const double tb = (sb[0] + sb[1]) + (sb[2] + sb[3]);
        const double tv = (double)((sv[0] + sv[1]) + (sv[2] + sv[3]));
        const double ta = (double)((sa[0] + sa[1]) + (sa[2] + sa[3]));
        const double bce = -tb / ((double)Sn * (double)Bn);
        const double mom = ta / ((double)Bn * (double)Bn * (double)Zn)
                         + tv / ((double)Zn * (double)Zn);
        out[0] = (float)(bce + mom);
    }
}

extern "C" void kernel_launch(void* const* d_in, const int* in_sizes, int n_in,
                              void* d_out, int out_size, void* d_ws, size_t ws_size,
                              hipStream_t stream)
{
    const float* x     = (const float*)d_in[0];
    const float* recon = (const float*)d_in[1];
    const float* mu    = (const float*)d_in[2];
    // d_in[3] = log_var: unused by the reference
    const float* masks = (const float*)d_in[4];
    const int*   lhs   = (const int*)d_in[5];
    float* out = (float*)d_out;
    char* ws = (char*)d_ws;

    hipMemsetAsync(ws + WS_VAR, 0, 12544 + 224, stream);   // atomic accumulators only
    setup_kernel<<<1, 256, 0, stream>>>(masks, lhs, ws);
    main_kernel<<<NBLK_TOT, 256, 0, stream>>>(x, recon, mu, ws);
    finalize_kernel<<<1, 256, 0, stream>>>(ws, out);
}

// Round 5
// 353.954 us; speedup vs baseline: 1.0988x; 1.0226x over previous
//
#include <hip/hip_runtime.h>
#include <math.h>

#define Bn 2048
#define Sn 277
#define Rn 80
#define Ln 12
#define Zn 56
#define NROWS (Bn * Sn)                   // 567296
#define ROWS_PER_BLK 64                   // rows per BCE block (1 row per quad)
#define NBLK_BCE (NROWS / ROWS_PER_BLK)   // 8864 exactly
#define NMOM 32                           // moment blocks
#define MROWS (Bn / NMOM)                 // 64 mu-rows per moment block
#define NBLK_TOT (NBLK_BCE + NMOM)

// ws layout (bytes):
//   [0,     1280)   u32  cmask_sw[80][4]  per-(rule,lane) 20-bit mask (setup)
//   [1280, 36736)   float bce_partial[8864]  one float PER BLOCK (no zeroing)
//   [36736, 49280)  float var_g[3136]     (atomicAdd -> memset 0)
//   [49280, 49504)  float avg_g[56]       (atomicAdd -> memset 0)
#define WS_CM  0
#define WS_BCE 1280
#define WS_VAR 36736
#define WS_AVG 49280

typedef float f4 __attribute__((ext_vector_type(4)));

__device__ __forceinline__ float qsum4(float v) {
    // butterfly sum within each 4-lane quad via DPP quad_perm (no DS ops)
    int t = __builtin_amdgcn_update_dpp(0, __float_as_int(v), 0xB1, 0xF, 0xF, true); // [1,0,3,2]
    v += __int_as_float(t);
    t = __builtin_amdgcn_update_dpp(0, __float_as_int(v), 0x4E, 0xF, 0xF, true);     // [2,3,0,1]
    v += __int_as_float(t);
    return v;
}

__global__ __launch_bounds__(256) void setup_kernel(
    const float* __restrict__ masks, const int* __restrict__ lhs, char* __restrict__ ws)
{
    unsigned* cmask_sw = (unsigned*)(ws + WS_CM);
    for (int idx = threadIdx.x; idx < Rn * 4; idx += 256) {
        const int r = idx >> 2, c = idx & 3;
        const int l = lhs[r];
        unsigned bits = 0u;
        for (int k = 0; k < 5; ++k)
            for (int comp = 0; comp < 4; ++comp) {
                const int j = 16 * k + 4 * c + comp;
                if (masks[l * Rn + j] > 0.5f) bits |= (1u << (4 * k + comp));
            }
        cmask_sw[idx] = bits;
    }
}

// Fetch-amplification fix. R4 evidence: nt quad-granule reads ran main at
// 106us == 726MB / 6.8TB/s (the fill kernel's demonstrated HBM rate) == 2x
// our 363MB footprint: with nt (no L2/L3 allocate) each 64B quad request
// fetches a 128B line whose other half is re-fetched by a different
// instruction. Fix = full-line consumption: each wave-load is one aligned
// 1024B span (8 fully-used 128B lines), nt-tagged, staged to LDS (rows
// padded 20->21 float4: bank aliasing 2-way only = free), then one row/quad
// from LDS. Every HBM line fetched exactly once.
__global__ __launch_bounds__(256, 3) void main_kernel(
    const float* __restrict__ x, const float* __restrict__ recon,
    const float* __restrict__ mu, char* __restrict__ ws)
{
    __shared__ f4 ldsb[2688];   // 43008 B -> 3 blocks/CU
    const int tid = threadIdx.x;

    if (blockIdx.x < NMOM) {
        // ---------------- moments: 32 blocks x 64 mu-rows ----------------
        float* var_g = (float*)(ws + WS_VAR);
        float* avg_g = (float*)(ws + WS_AVG);
        float* sm = (float*)ldsb;                     // 64*56 floats = 14336 B
        const int m = blockIdx.x;
        const float* src = mu + (size_t)m * MROWS * Zn;
        for (int i = tid; i < MROWS * Zn; i += 256) sm[i] = src[i];
        __syncthreads();

        #pragma unroll 1
        for (int k = 0; k < 13; ++k) {
            const int p = tid + 256 * k;
            if (p < Zn * Zn) {
                const int i = p / Zn, j = p - i * Zn;
                float a = 0.0f;
                #pragma unroll 8
                for (int r = 0; r < MROWS; ++r) a = fmaf(sm[r * Zn + i], sm[r * Zn + j], a);
                atomicAdd(&var_g[p], a);
            }
        }
        if (tid < Zn) {
            float s = 0.0f;
            #pragma unroll 8
            for (int r = 0; r < MROWS; ++r) s += sm[r * Zn + tid];
            atomicAdd(&avg_g[tid], s);
        }
        return;
    }

    // ---------------- BCE: stage 64 rows full-line nt -> LDS, 1 row/quad ----------------
    const int bid = blockIdx.x - NMOM;
    const unsigned* cmask_sw = (const unsigned*)(ws + WS_CM);
    float* bce_partial = (float*)(ws + WS_BCE);

    const size_t base = (size_t)bid * (ROWS_PER_BLK * (Rn / 4));   // 1280 float4
    const f4* xg = (const f4*)x + base;
    const f4* rg = (const f4*)recon + base;

    // 10 fully-coalesced 1024-B nt wave-loads (5 x, 5 recon): 8 full lines each
    f4 tv[10];
    #pragma unroll
    for (int i = 0; i < 5; ++i) tv[i]     = __builtin_nontemporal_load(&xg[256 * i + tid]);
    #pragma unroll
    for (int i = 0; i < 5; ++i) tv[5 + i] = __builtin_nontemporal_load(&rg[256 * i + tid]);
    #pragma unroll
    for (int i = 0; i < 5; ++i) {
        const int f = 256 * i + tid;            // 0..1279
        const int row = f / 20, col = f - 20 * row;
        ldsb[row * 21 + col]        = tv[i];     // x region, padded rows
        ldsb[1344 + row * 21 + col] = tv[5 + i]; // recon region (1344 = 64*21)
    }
    __syncthreads();

    const int qq = tid >> 2;             // quad = row within tile (0..63)
    const int c  = tid & 3;              // lane within quad
    const int sb = qq * 21 + c;

    f4 X[5], Rv[5];
    #pragma unroll
    for (int k = 0; k < 5; ++k) X[k]  = ldsb[sb + 4 * k];
    #pragma unroll
    for (int k = 0; k < 5; ++k) Rv[k] = ldsb[1344 + sb + 4 * k];

    auto dotc = [](const f4 v, float base_) {
        return fmaf(v.x, base_, fmaf(v.y, base_ + 1.f, fmaf(v.z, base_ + 2.f, v.w * (base_ + 3.f))));
    };

    float ss = 0.0f;
    {
        // argmax via dot with index weights (x is exactly one-hot)
        float dl = dotc(X[0], 0.f) + dotc(X[1], 16.f) + dotc(X[2], 32.f)
                 + dotc(X[3], 48.f) + dotc(X[4], 64.f);
        float xs = 0.f;
        #pragma unroll
        for (int k = 0; k < 5; ++k)
            xs += ((X[k].x + X[k].y) + (X[k].z + X[k].w));
        dl = fmaf((float)(4 * c), xs, dl);
        const int amax = (int)(qsum4(dl) + 0.5f);

        const unsigned bits = cmask_sw[(amax << 2) | c];   // L1-hot dword

        // mask in place (reuse Rv registers)
        #pragma unroll
        for (int k = 0; k < 5; ++k) {
            Rv[k].x = ((bits >> (4 * k + 0)) & 1u) ? Rv[k].x : 0.f;
            Rv[k].y = ((bits >> (4 * k + 1)) & 1u) ? Rv[k].y : 0.f;
            Rv[k].z = ((bits >> (4 * k + 2)) & 1u) ? Rv[k].z : 0.f;
            Rv[k].w = ((bits >> (4 * k + 3)) & 1u) ? Rv[k].w : 0.f;
        }
        float dd = 0.f;
        #pragma unroll
        for (int k = 0; k < 5; ++k)
            dd += ((Rv[k].x + Rv[k].y) + (Rv[k].z + Rv[k].w));
        const float invd = __builtin_amdgcn_rcpf(qsum4(dd));

        const int ka = amax >> 4;
        const int ca = (amax >> 2) & 3;
        const int comp = amax & 3;
        const bool owner = (c == ca);

        // sum(log(1-t)) = log(prod(1-t)); product can only hit 0 if some t==1
        // exactly -> guarded per-element fallback (from regs) keeps clamp semantics.
        float p = 1.0f;
        float ta = 1.0f;
        #pragma unroll
        for (int k = 0; k < 5; ++k) {
            const float t0 = fminf(Rv[k].x * invd, 1.f);
            const float t1 = fminf(Rv[k].y * invd, 1.f);
            const float t2 = fminf(Rv[k].z * invd, 1.f);
            const float t3 = fminf(Rv[k].w * invd, 1.f);
            p *= ((1.f - t0) * (1.f - t1)) * ((1.f - t2) * (1.f - t3));
            if (owner && k == ka)
                ta = (comp == 0) ? t0 : (comp == 1) ? t1 : (comp == 2) ? t2 : t3;
        }
        if (p > 0.0f) {
            ss += __builtin_amdgcn_logf(p) * 0.69314718055994531f;   // log2 -> ln
        } else {
            // astronomically rare: per-element with clamps (data already in regs)
            #pragma unroll
            for (int k = 0; k < 5; ++k) {
                ss += fmaxf(__logf(1.f - fminf(Rv[k].x * invd, 1.f)), -100.f)
                    + fmaxf(__logf(1.f - fminf(Rv[k].y * invd, 1.f)), -100.f)
                    + fmaxf(__logf(1.f - fminf(Rv[k].z * invd, 1.f)), -100.f)
                    + fmaxf(__logf(1.f - fminf(Rv[k].w * invd, 1.f)), -100.f);
            }
        }
        if (owner)
            ss += fmaxf(__logf(ta), -100.f) - fmaxf(__logf(1.f - ta), -100.f);
    }

    // quad DPP + 4 shuffles -> wave sums; block-reduce via 4 floats of LDS
    ss = qsum4(ss);
    ss += __shfl_xor(ss, 4);
    ss += __shfl_xor(ss, 8);
    ss += __shfl_xor(ss, 16);
    ss += __shfl_xor(ss, 32);
    __syncthreads();                      // all ds_reads of the tile retired
    float* smf = (float*)ldsb;
    if ((tid & 63) == 0) smf[tid >> 6] = ss;
    __syncthreads();
    if (tid == 0)
        bce_partial[bid] = (smf[0] + smf[1]) + (smf[2] + smf[3]);
}

__global__ __launch_bounds__(256) void finalize_kernel(
    const char* __restrict__ ws, float* __restrict__ out)
{
    const float* bce_partial = (const float*)(ws + WS_BCE);
    const float* var_g = (const float*)(ws + WS_VAR);
    const float* avg_g = (const float*)(ws + WS_AVG);
    __shared__ double sb[4];
    __shared__ float sv[4], sa[4];
    const int tid = threadIdx.x;

    double bsum = 0.0;
    for (int i = tid; i < NBLK_BCE; i += 256) bsum += (double)bce_partial[i];

    float vsum = 0.0f;
    for (int p = tid; p < Zn * Zn; p += 256) {
        const int i = p / Zn, j = p - i * Zn;
        const float e = var_g[p] * (1.0f / (float)Bn) - ((i == j) ? 1.0f : 0.0f);
        vsum += fabsf(e);
    }
    float asum = 0.0f;
    for (int z = tid; z < Zn; z += 256) { const float a = avg_g[z]; asum += a * a; }

    #pragma unroll
    for (int o = 32; o; o >>= 1) {
        bsum += __shfl_xor(bsum, o);
        vsum += __shfl_xor(vsum, o);
        asum += __shfl_xor(asum, o);
    }
    if ((tid & 63) == 0) { const int w = tid >> 6; sb[w] = bsum; sv[w] = vsum; sa[w] = asum; }
    __syncthreads();
    if (tid == 0) {
        const double tb = (sb[0] + sb[1]) + (sb[2] + sb[3]);
        const double tv = (double)((sv[0] + sv[1]) + (sv[2] + sv[3]));
        const double ta = (double)((sa[0] + sa[1]) + (sa[2] + sa[3]));
        const double bce = -tb / ((double)Sn * (double)Bn);
        const double mom = ta / ((double)Bn * (double)Bn * (double)Zn)
                         + tv / ((double)Zn * (double)Zn);
        out[0] = (float)(bce + mom);
    }
}

extern "C" void kernel_launch(void* const* d_in, const int* in_sizes, int n_in,
                              void* d_out, int out_size, void* d_ws, size_t ws_size,
                              hipStream_t stream)
{
    const float* x     = (const float*)d_in[0];
    const float* recon = (const float*)d_in[1];
    const float* mu    = (const float*)d_in[2];
    // d_in[3] = log_var: unused by the reference
    const float* masks = (const float*)d_in[4];
    const int*   lhs   = (const int*)d_in[5];
    float* out = (float*)d_out;
    char* ws = (char*)d_ws;

    hipMemsetAsync(ws + WS_VAR, 0, 12544 + 224, stream);   // atomic accumulators only
    setup_kernel<<<1, 256, 0, stream>>>(masks, lhs, ws);
    main_kernel<<<NBLK_TOT, 256, 0, stream>>>(x, recon, mu, ws);
    finalize_kernel<<<1, 256, 0, stream>>>(ws, out);
}